// Round 11
// baseline (487.176 us; speedup 1.0000x reference)
//
#include <hip/hip_runtime.h>
#include <hip/hip_bf16.h>
#include <math.h>

// ---------- types / helpers ----------
using u16 = unsigned short;
typedef __bf16 bf16x8 __attribute__((ext_vector_type(8)));
typedef float f32x4 __attribute__((ext_vector_type(4)));
typedef u16 u16x8 __attribute__((ext_vector_type(8)));

__device__ __forceinline__ u16 f2b(float f) {
  union { float f; unsigned u; } c; c.f = f;
  unsigned r = c.u + 0x7fffu + ((c.u >> 16) & 1u);
  return (u16)(r >> 16);
}
__device__ __forceinline__ float b2f(u16 h) {
  union { unsigned u; float f; } c; c.u = ((unsigned)h) << 16;
  return c.f;
}

// tanh-form GELU (max |err| vs exact ~3e-4 << bf16 rounding)
__device__ __forceinline__ float fast_gelu(float t) {
  float y = fminf(1.5957691216f * t + 0.07135481283f * t * t * t, 80.f);
  float e = __expf(y);
  return t * e * (1.0f / (e + 1.0f));
}

#define EPI_BF16 0
#define EPI_EXP_SUM 1
#define EPI_GELU_BIAS 2
#define EPI_BF16_BIAS 4

#define GLDS16(src, dst)                                                     \
  __builtin_amdgcn_global_load_lds(                                          \
      (const __attribute__((address_space(1))) void*)(src),                  \
      (__attribute__((address_space(3))) void*)(dst), 16, 0, 0)

// bijective XCD swizzle (m204)
__device__ __forceinline__ int xswz(int o, int n) {
  int q = n >> 3, r = n & 7, x = o & 7, i = o >> 3;
  return (x < r ? x * (q + 1) : r * (q + 1) + (x - r) * q) + i;
}

template <int EPI>
__device__ __forceinline__ void epi_store(
    void* Cg, const float* bias, float v, long long off, int ccol, float scale)
{
  if (EPI == EPI_BF16) {
    ((u16*)Cg)[off] = f2b(v);
  } else if (EPI == EPI_GELU_BIAS) {
    ((u16*)Cg)[off] = f2b(fast_gelu(v + bias[ccol]));
  } else {  // EPI_BF16_BIAS
    ((u16*)Cg)[off] = f2b(v + bias[ccol]);
  }
}

// ---------- 256x256 4-phase bf16 GEMM (v3: r4 skeleton + reg frag read-ahead) -
// 512 thr = 8 waves (2Mx4N); per-wave 128x64 = acc[8][4]; BK=64 kk0/kk1 panels.
// v3: ph0 pre-reads ph1's A-frags (same kk0 panel/guard window) before the MFMA
// burst so their LDS latency hides under MFMA; same for ph2->ph3. Barrier and
// vmcnt guard positions are UNCHANGED from the r4-proven schedule.
template <int EPI>
__global__ __launch_bounds__(512, 2) void gemm256(
    const u16* __restrict__ Ag, const u16* __restrict__ Bg,
    void* __restrict__ Cg, const float* __restrict__ bias,
    int nbx, int K, float scale, int lda, int ldb, int ldc,
    long long sAz, long long sBz, long long sCz,
    float* __restrict__ lsum, int lzs)
{
  __shared__ __align__(16) u16 lds[65536];  // 131072 B

  const int tid = threadIdx.x;
  const int wave = tid >> 6, lane = tid & 63;
  const int wr = wave >> 2, wc = wave & 3;
  const int id = xswz(blockIdx.x, gridDim.x);
  const int bx = id % nbx, by = id / nbx;
  const int m0 = by * 256, n0 = bx * 256;
  const long long z = blockIdx.z;
  const u16* A = Ag + z * sAz + (long long)m0 * lda;
  const u16* B = Bg + z * sBz + (long long)n0 * ldb;

  const int rA = wave * 32 + (lane >> 2);
  const int slot = (lane & 3) ^ ((rA >> 1) & 3);  // inverse-swizzled source slot
  const u16* a0 = A + (long long)rA * lda + slot * 8;
  const u16* a1 = a0 + (long long)16 * lda;
  const u16* b0 = B + (long long)rA * ldb + slot * 8;
  const u16* b1 = b0 + (long long)16 * ldb;
  const int d0 = wave * 32 * 32;
  const int d1 = (wave * 32 + 16) * 32;

  int offA[8], offB[4];
#pragma unroll
  for (int mf = 0; mf < 8; ++mf) {
    int r = wr * 128 + mf * 16 + (lane & 15);
    int b = r * 64 + ((lane >> 4) << 4);
    offA[mf] = b ^ (((b >> 7) & 3) << 4);
  }
#pragma unroll
  for (int nf = 0; nf < 4; ++nf) {
    int r = wc * 64 + nf * 16 + (lane & 15);
    int b = r * 64 + ((lane >> 4) << 4);
    offB[nf] = b ^ (((b >> 7) & 3) << 4);
  }

  f32x4 acc[8][4];
#pragma unroll
  for (int m = 0; m < 8; ++m)
#pragma unroll
    for (int n = 0; n < 4; ++n) acc[m][n] = f32x4{0.f, 0.f, 0.f, 0.f};

  const char* ldsc = (const char*)lds;
  const int NT = K >> 6;

  // prologue: tile 0 -> buf 0 (A-kk0, B-kk0, A-kk1, B-kk1)
  GLDS16(a0, lds + 0 * 8192 + d0);  GLDS16(a1, lds + 0 * 8192 + d1);
  GLDS16(b0, lds + 2 * 8192 + d0);  GLDS16(b1, lds + 2 * 8192 + d1);
  GLDS16(a0 + 32, lds + 1 * 8192 + d0);  GLDS16(a1 + 32, lds + 1 * 8192 + d1);
  GLDS16(b0 + 32, lds + 3 * 8192 + d0);  GLDS16(b1 + 32, lds + 3 * 8192 + d1);
  asm volatile("s_waitcnt vmcnt(4)" ::: "memory");
  asm volatile("s_barrier" ::: "memory");

  for (int t = 0; t < NT; ++t) {
    const int buf = t & 1, nb = buf ^ 1;
    const int kc = (t + 1 < NT) ? ((t + 1) << 6) : 0;
    const char* pA0 = ldsc + (buf * 4 + 0) * 16384;
    const char* pA1 = ldsc + (buf * 4 + 1) * 16384;
    const char* pB0 = ldsc + (buf * 4 + 2) * 16384;
    const char* pB1 = ldsc + (buf * 4 + 3) * 16384;
    u16* q = lds + nb * 4 * 8192;

    bf16x8 F0a[4], F1a[4], Bf[4];

    // phase 0: stage next A-kk0; read F0 (A m0-3 + B, kk0); barrier;
    //          pre-read F1 (A m4-7 kk0); MFMA(F0); barrier
    GLDS16(a0 + kc, q + 0 * 8192 + d0);
    GLDS16(a1 + kc, q + 0 * 8192 + d1);
#pragma unroll
    for (int m = 0; m < 4; ++m) F0a[m] = *(const bf16x8*)(pA0 + offA[m]);
#pragma unroll
    for (int n = 0; n < 4; ++n) Bf[n] = *(const bf16x8*)(pB0 + offB[n]);
    asm volatile("s_barrier" ::: "memory");
#pragma unroll
    for (int m = 0; m < 4; ++m) F1a[m] = *(const bf16x8*)(pA0 + offA[4 + m]);
    __builtin_amdgcn_s_setprio(1);
#pragma unroll
    for (int m = 0; m < 4; ++m)
#pragma unroll
      for (int n = 0; n < 4; ++n)
        acc[m][n] = __builtin_amdgcn_mfma_f32_16x16x32_bf16(F0a[m], Bf[n], acc[m][n], 0, 0, 0);
    __builtin_amdgcn_s_setprio(0);
    asm volatile("s_barrier" ::: "memory");

    // phase 1: stage next B-kk0; barrier; MFMA(F1, pre-read); guard; barrier
    GLDS16(b0 + kc, q + 2 * 8192 + d0);
    GLDS16(b1 + kc, q + 2 * 8192 + d1);
    asm volatile("s_barrier" ::: "memory");
    __builtin_amdgcn_s_setprio(1);
#pragma unroll
    for (int m = 0; m < 4; ++m)
#pragma unroll
      for (int n = 0; n < 4; ++n)
        acc[4 + m][n] = __builtin_amdgcn_mfma_f32_16x16x32_bf16(F1a[m], Bf[n], acc[4 + m][n], 0, 0, 0);
    __builtin_amdgcn_s_setprio(0);
    asm volatile("s_waitcnt vmcnt(4)" ::: "memory");  // kk1(t) landed
    asm volatile("s_barrier" ::: "memory");

    // phase 2: stage next A-kk1; read F0'(A m0-3 + B, kk1); barrier;
    //          pre-read F1'(A m4-7 kk1); MFMA; barrier
    GLDS16(a0 + kc + 32, q + 1 * 8192 + d0);
    GLDS16(a1 + kc + 32, q + 1 * 8192 + d1);
#pragma unroll
    for (int m = 0; m < 4; ++m) F0a[m] = *(const bf16x8*)(pA1 + offA[m]);
#pragma unroll
    for (int n = 0; n < 4; ++n) Bf[n] = *(const bf16x8*)(pB1 + offB[n]);
    asm volatile("s_barrier" ::: "memory");
#pragma unroll
    for (int m = 0; m < 4; ++m) F1a[m] = *(const bf16x8*)(pA1 + offA[4 + m]);
    __builtin_amdgcn_s_setprio(1);
#pragma unroll
    for (int m = 0; m < 4; ++m)
#pragma unroll
      for (int n = 0; n < 4; ++n)
        acc[m][n] = __builtin_amdgcn_mfma_f32_16x16x32_bf16(F0a[m], Bf[n], acc[m][n], 0, 0, 0);
    __builtin_amdgcn_s_setprio(0);
    asm volatile("s_barrier" ::: "memory");

    // phase 3: stage next B-kk1; barrier; MFMA(F1', pre-read); guard; barrier
    GLDS16(b0 + kc + 32, q + 3 * 8192 + d0);
    GLDS16(b1 + kc + 32, q + 3 * 8192 + d1);
    asm volatile("s_barrier" ::: "memory");
    __builtin_amdgcn_s_setprio(1);
#pragma unroll
    for (int m = 0; m < 4; ++m)
#pragma unroll
      for (int n = 0; n < 4; ++n)
        acc[4 + m][n] = __builtin_amdgcn_mfma_f32_16x16x32_bf16(F1a[m], Bf[n], acc[4 + m][n], 0, 0, 0);
    __builtin_amdgcn_s_setprio(0);
    asm volatile("s_waitcnt vmcnt(4)" ::: "memory");  // kk0(t+1) landed
    asm volatile("s_barrier" ::: "memory");
  }

  if (EPI == EPI_EXP_SUM) {
    // P' = exp(v*scale) bf16; accumulate row sums (over this block's 256 cols)
#pragma unroll
    for (int mf = 0; mf < 8; ++mf) {
      const int crow = m0 + wr * 128 + mf * 16 + (lane >> 4) * 4;
      float part[4] = {0.f, 0.f, 0.f, 0.f};
#pragma unroll
      for (int nf = 0; nf < 4; ++nf) {
        const int ccol = n0 + wc * 64 + nf * 16 + (lane & 15);
#pragma unroll
        for (int j = 0; j < 4; ++j) {
          const float p = __expf(fminf(acc[mf][nf][j] * scale, 60.f));
          const u16 ub = f2b(p);
          ((u16*)Cg)[(long long)(crow + j) * ldc + ccol + z * sCz] = ub;
          part[j] += b2f(ub);  // sum the rounded value PV will read
        }
      }
#pragma unroll
      for (int j = 0; j < 4; ++j) {
        float s = part[j];
        s += __shfl_xor(s, 1); s += __shfl_xor(s, 2);
        s += __shfl_xor(s, 4); s += __shfl_xor(s, 8);
        if ((lane & 15) == 0)
          atomicAdd(&lsum[(long long)z * lzs + crow + j], s);
      }
    }
  } else {
#pragma unroll
    for (int mf = 0; mf < 8; ++mf) {
#pragma unroll
      for (int nf = 0; nf < 4; ++nf) {
        const int crow = m0 + wr * 128 + mf * 16 + (lane >> 4) * 4;
        const int ccol = n0 + wc * 64 + nf * 16 + (lane & 15);
#pragma unroll
        for (int j = 0; j < 4; ++j) {
          const long long off = (long long)(crow + j) * ldc + ccol + z * sCz;
          epi_store<EPI>(Cg, bias, acc[mf][nf][j], off, ccol, scale);
        }
      }
    }
  }
}

// ---------- 128x128 2-phase bf16 GEMM (r4 schedule), 2 blocks/CU ----------
template <int EPI>
__global__ __launch_bounds__(256, 2) void gemm128(
    const u16* __restrict__ Ag, const u16* __restrict__ Bg,
    void* __restrict__ Cg, const float* __restrict__ bias,
    int nbx, int K, float scale, int lda, int ldb, int ldc,
    long long sAz, long long sBz, long long sCz)
{
  __shared__ __align__(16) u16 lds[32768];  // 65536 B

  const int tid = threadIdx.x;
  const int wave = tid >> 6, lane = tid & 63;
  const int wr = wave >> 1, wc = wave & 1;
  const int id = xswz(blockIdx.x, gridDim.x);
  const int bx = id % nbx, by = id / nbx;
  const int m0 = by * 128, n0 = bx * 128;
  const long long z = blockIdx.z;
  const u16* A = Ag + z * sAz + (long long)m0 * lda;
  const u16* B = Bg + z * sBz + (long long)n0 * ldb;

  const int rA = wave * 32 + (lane >> 2);
  const int slot = (lane & 3) ^ ((rA >> 1) & 3);
  const u16* a0 = A + (long long)rA * lda + slot * 8;
  const u16* a1 = a0 + (long long)16 * lda;
  const u16* b0 = B + (long long)rA * ldb + slot * 8;
  const u16* b1 = b0 + (long long)16 * ldb;
  const int d0 = wave * 32 * 32;
  const int d1 = (wave * 32 + 16) * 32;

  int offA[4], offB[4];
#pragma unroll
  for (int f = 0; f < 4; ++f) {
    int ra = wr * 64 + f * 16 + (lane & 15);
    int ba = ra * 64 + ((lane >> 4) << 4);
    offA[f] = ba ^ (((ba >> 7) & 3) << 4);
    int rb = wc * 64 + f * 16 + (lane & 15);
    int bb = rb * 64 + ((lane >> 4) << 4);
    offB[f] = bb ^ (((bb >> 7) & 3) << 4);
  }

  f32x4 acc[4][4];
#pragma unroll
  for (int m = 0; m < 4; ++m)
#pragma unroll
    for (int n = 0; n < 4; ++n) acc[m][n] = f32x4{0.f, 0.f, 0.f, 0.f};

  const char* ldsc = (const char*)lds;
  const int NT = K >> 6;

  GLDS16(a0, lds + 0 * 4096 + d0);  GLDS16(a1, lds + 0 * 4096 + d1);
  GLDS16(b0, lds + 2 * 4096 + d0);  GLDS16(b1, lds + 2 * 4096 + d1);
  GLDS16(a0 + 32, lds + 1 * 4096 + d0);  GLDS16(a1 + 32, lds + 1 * 4096 + d1);
  GLDS16(b0 + 32, lds + 3 * 4096 + d0);  GLDS16(b1 + 32, lds + 3 * 4096 + d1);
  asm volatile("s_waitcnt vmcnt(4)" ::: "memory");
  asm volatile("s_barrier" ::: "memory");

  for (int t = 0; t < NT; ++t) {
    const int buf = t & 1, nb = buf ^ 1;
    const int kc = (t + 1 < NT) ? ((t + 1) << 6) : 0;
    const char* pA0 = ldsc + (buf * 4 + 0) * 8192;
    const char* pA1 = ldsc + (buf * 4 + 1) * 8192;
    const char* pB0 = ldsc + (buf * 4 + 2) * 8192;
    const char* pB1 = ldsc + (buf * 4 + 3) * 8192;
    u16* q = lds + nb * 4 * 4096;

    bf16x8 Af[4], Bf[4];

    // phase 0: kk0 (stage next A-kk0 + B-kk0)
    GLDS16(a0 + kc, q + 0 * 4096 + d0);  GLDS16(a1 + kc, q + 0 * 4096 + d1);
    GLDS16(b0 + kc, q + 2 * 4096 + d0);  GLDS16(b1 + kc, q + 2 * 4096 + d1);
#pragma unroll
    for (int m = 0; m < 4; ++m) Af[m] = *(const bf16x8*)(pA0 + offA[m]);
#pragma unroll
    for (int n = 0; n < 4; ++n) Bf[n] = *(const bf16x8*)(pB0 + offB[n]);
    asm volatile("s_barrier" ::: "memory");
    __builtin_amdgcn_s_setprio(1);
#pragma unroll
    for (int m = 0; m < 4; ++m)
#pragma unroll
      for (int n = 0; n < 4; ++n)
        acc[m][n] = __builtin_amdgcn_mfma_f32_16x16x32_bf16(Af[m], Bf[n], acc[m][n], 0, 0, 0);
    __builtin_amdgcn_s_setprio(0);
    asm volatile("s_waitcnt vmcnt(4)" ::: "memory");
    asm volatile("s_barrier" ::: "memory");

    // phase 1: kk1 (stage next A-kk1 + B-kk1)
    GLDS16(a0 + kc + 32, q + 1 * 4096 + d0);  GLDS16(a1 + kc + 32, q + 1 * 4096 + d1);
    GLDS16(b0 + kc + 32, q + 3 * 4096 + d0);  GLDS16(b1 + kc + 32, q + 3 * 4096 + d1);
#pragma unroll
    for (int m = 0; m < 4; ++m) Af[m] = *(const bf16x8*)(pA1 + offA[m]);
#pragma unroll
    for (int n = 0; n < 4; ++n) Bf[n] = *(const bf16x8*)(pB1 + offB[n]);
    asm volatile("s_barrier" ::: "memory");
    __builtin_amdgcn_s_setprio(1);
#pragma unroll
    for (int m = 0; m < 4; ++m)
#pragma unroll
      for (int n = 0; n < 4; ++n)
        acc[m][n] = __builtin_amdgcn_mfma_f32_16x16x32_bf16(Af[m], Bf[n], acc[m][n], 0, 0, 0);
    __builtin_amdgcn_s_setprio(0);
    asm volatile("s_waitcnt vmcnt(4)" ::: "memory");
    asm volatile("s_barrier" ::: "memory");
  }

#pragma unroll
  for (int mf = 0; mf < 4; ++mf) {
#pragma unroll
    for (int nf = 0; nf < 4; ++nf) {
      const int crow = m0 + wr * 64 + mf * 16 + (lane >> 4) * 4;
      const int ccol = n0 + wc * 64 + nf * 16 + (lane & 15);
#pragma unroll
      for (int j = 0; j < 4; ++j) {
        const long long off = (long long)(crow + j) * ldc + ccol + z * sCz;
        epi_store<EPI>(Cg, bias, acc[mf][nf][j], off, ccol, scale);
      }
    }
  }
}

// ---------- zero f32 buffer ----------
__global__ __launch_bounds__(256) void zero_f32(float* __restrict__ p, int n) {
  const int i = blockIdx.x * 256 + threadIdx.x;
  if (i < n) p[i] = 0.f;
}

// ---------- cast x fp32 -> bf16 ----------
__global__ __launch_bounds__(256) void cast_f32_bf16(
    const float* __restrict__ x, u16* __restrict__ y, long long n4)
{
  const long long i = (long long)blockIdx.x * 256 + threadIdx.x;
  if (i >= n4) return;
  const float4 v = ((const float4*)x)[i];
  ushort4 o;
  o.x = f2b(v.x); o.y = f2b(v.y); o.z = f2b(v.z); o.w = f2b(v.w);
  ((ushort4*)y)[i] = o;
}

// ---------- transpose (+cast) : dst[c*R + r] = src[r*ldsrc + c] ----------
template <bool SRC_BF16>
__global__ __launch_bounds__(256) void transpose_cast(
    const void* __restrict__ srcv, u16* __restrict__ dst, int R, int C, int ldsrc,
    long long szSrc, long long szDst)
{
  __shared__ float tile[32][33];
  const long long zs = (long long)blockIdx.z * szSrc;
  const long long zd = (long long)blockIdx.z * szDst;
  const int c0 = blockIdx.x * 32, r0 = blockIdx.y * 32;
  const int tx = threadIdx.x & 31, ty = threadIdx.x >> 5;
#pragma unroll
  for (int i = 0; i < 4; ++i) {
    const int r = r0 + ty + i * 8;
    float v;
    if (SRC_BF16) v = b2f(((const u16*)srcv)[zs + (long long)r * ldsrc + c0 + tx]);
    else          v = ((const float*)srcv)[zs + (long long)r * ldsrc + c0 + tx];
    tile[ty + i * 8][tx] = v;
  }
  __syncthreads();
#pragma unroll
  for (int i = 0; i < 4; ++i) {
    const int c = c0 + ty + i * 8;
    dst[zd + (long long)c * R + r0 + tx] = f2b(tile[tx][ty + i * 8]);
  }
}

// ---------- add + layernorm (LN1: bf16 x + O'/l) ----------
__global__ __launch_bounds__(256) void ln1_kernel(
    const u16* __restrict__ xb, const u16* __restrict__ O,
    const float* __restrict__ l,
    const float* __restrict__ g, const float* __restrict__ be,
    u16* __restrict__ h)
{
  __shared__ float red[8];
  const long long row = blockIdx.x;
  const u16* xr = xb + row * 768;
  const u16* orow = O + row * 768;
  const float invl = 1.0f / l[row];
  const int t = threadIdx.x, base = t * 3;

  float v[3];
#pragma unroll
  for (int j = 0; j < 3; ++j) v[j] = b2f(xr[base + j]) + b2f(orow[base + j]) * invl;
  float s = v[0] + v[1] + v[2];
  float ss = v[0] * v[0] + v[1] * v[1] + v[2] * v[2];
  for (int o = 32; o; o >>= 1) { s += __shfl_xor(s, o); ss += __shfl_xor(ss, o); }
  if ((t & 63) == 0) { red[t >> 6] = s; red[4 + (t >> 6)] = ss; }
  __syncthreads();
  s = red[0] + red[1] + red[2] + red[3];
  ss = red[4] + red[5] + red[6] + red[7];
  const float mu = s * (1.0f / 768.0f);
  const float var = ss * (1.0f / 768.0f) - mu * mu;
  const float inv = rsqrtf(var + 1e-5f);
#pragma unroll
  for (int j = 0; j < 3; ++j) {
    const float o = (v[j] - mu) * inv * g[base + j] + be[base + j];
    h[row * 768 + base + j] = f2b(o);
  }
}

__global__ __launch_bounds__(256) void ln2_kernel(
    const u16* __restrict__ h, const u16* __restrict__ ob,
    const float* __restrict__ g, const float* __restrict__ be,
    float* __restrict__ y)
{
  __shared__ float red[8];
  const long long row = blockIdx.x;
  const u16* hr = h + row * 768;
  const u16* orow = ob + row * 768;
  const int t = threadIdx.x, base = t * 3;

  float v[3];
#pragma unroll
  for (int j = 0; j < 3; ++j) v[j] = b2f(hr[base + j]) + b2f(orow[base + j]);
  float s = v[0] + v[1] + v[2];
  float ss = v[0] * v[0] + v[1] * v[1] + v[2] * v[2];
  for (int o = 32; o; o >>= 1) { s += __shfl_xor(s, o); ss += __shfl_xor(ss, o); }
  if ((t & 63) == 0) { red[t >> 6] = s; red[4 + (t >> 6)] = ss; }
  __syncthreads();
  s = red[0] + red[1] + red[2] + red[3];
  ss = red[4] + red[5] + red[6] + red[7];
  const float mu = s * (1.0f / 768.0f);
  const float var = ss * (1.0f / 768.0f) - mu * mu;
  const float inv = rsqrtf(var + 1e-5f);
#pragma unroll
  for (int j = 0; j < 3; ++j) {
    y[row * 768 + base + j] = (v[j] - mu) * inv * g[base + j] + be[base + j];
  }
}

// ---------- launch ----------
extern "C" void kernel_launch(void* const* d_in, const int* in_sizes, int n_in,
                              void* d_out, int out_size, void* d_ws, size_t ws_size,
                              hipStream_t stream)
{
  const int Bb = 8, Nn = 2048, D = 768, F = 3072, E = 1536;
  const int M = Bb * Nn;
  const long long MD = (long long)M * D;

  const float* x   = (const float*)d_in[0];
  const float* Wq  = (const float*)d_in[1];
  const float* Wk  = (const float*)d_in[2];
  const float* Wv  = (const float*)d_in[3];
  const float* g1  = (const float*)d_in[4];
  const float* be1 = (const float*)d_in[5];
  const float* W1  = (const float*)d_in[6];
  const float* b1  = (const float*)d_in[7];
  const float* W2  = (const float*)d_in[8];
  const float* b2  = (const float*)d_in[9];
  const float* g2  = (const float*)d_in[10];
  const float* be2 = (const float*)d_in[11];

  // d_out carve: xb + Wq/Wk^T fused + Wv^T (all dead before ln2 writes d_out)
  u16* xb   = (u16*)d_out;                 // [16384][768]
  u16* wqkt = xb + MD;                     // [1536][768]
  u16* wvt  = wqkt + (size_t)E * D;        // [768][768]

  // ws carve
  char* w = (char*)d_ws;
  size_t off = 0;
  auto alloc = [&](size_t bytes) { void* p = w + off; off += bytes; return p; };
  u16* w1t = (u16*)alloc((size_t)F * D * 2);        // [3072][768]
  u16* w2t = (u16*)alloc((size_t)D * F * 2);        // [768][3072]
  u16* hb  = (u16*)alloc((size_t)MD * 2);           // LN1 out
  float* lrow = (float*)alloc((size_t)M * 4);       // softmax row sums
  u16* qk  = (u16*)alloc((size_t)M * E * 2);        // [16384][1536]
  u16* Vt  = (u16*)alloc((size_t)Bb * D * Nn * 2);  // [8][768][2048]
  u16* S   = (u16*)alloc((size_t)Bb * Nn * Nn * 2); // [8][2048][2048] (P')
  u16* O   = (u16*)alloc((size_t)MD * 2);
  // phase-B overlays on dead attention block:
  u16* hidden = qk;                                  // [16384][3072]
  u16* outf   = qk + (size_t)M * F;                  // bf16 FFN2 out

  const dim3 tcb(256);
  const float scl = 0.03608439182435161f;  // 1/sqrt(768)

  // 0) zero row-sum buffer; casts + weight transposes
  zero_f32<<<M / 256, 256, 0, stream>>>(lrow, M);
  cast_f32_bf16<<<(unsigned)(MD / 4 / 256), 256, 0, stream>>>(x, xb, MD / 4);
  transpose_cast<false><<<dim3(D / 32, D / 32, 1), tcb, 0, stream>>>(Wq, wqkt, D, D, D, 0, 0);
  transpose_cast<false><<<dim3(D / 32, D / 32, 1), tcb, 0, stream>>>(Wk, wqkt + D * D, D, D, D, 0, 0);
  transpose_cast<false><<<dim3(D / 32, D / 32, 1), tcb, 0, stream>>>(Wv, wvt, D, D, D, 0, 0);
  transpose_cast<false><<<dim3(F / 32, D / 32, 1), tcb, 0, stream>>>(W1, w1t, D, F, F, 0, 0);
  transpose_cast<false><<<dim3(D / 32, F / 32, 1), tcb, 0, stream>>>(W2, w2t, F, D, D, 0, 0);

  // 1) fused QK projection (gemm256: 384 blocks)
  gemm256<EPI_BF16><<<dim3(6 * 64, 1, 1), 512, 0, stream>>>(
      xb, wqkt, qk, nullptr, 6, D, 1.f, D, D, E, 0, 0, 0, nullptr, 0);

  // 2) Vt as GEMM: Vt[z][d][n] = wvt[d][:] . x[z][n][:]  (gemm128: 768 blocks)
  gemm128<EPI_BF16><<<dim3(16 * 6, 1, Bb), 256, 0, stream>>>(
      wvt, xb, Vt, nullptr, 16, D, 1.f, D, D, Nn,
      0, (long long)Nn * D, (long long)D * Nn);

  // 3) P' = exp(Q K^T / sqrt(D)) + row sums  (gemm256: 512 blocks)
  gemm256<EPI_EXP_SUM><<<dim3(8 * 8, 1, Bb), 512, 0, stream>>>(
      qk, qk + D, S, nullptr, 8, D, scl, E, E, Nn,
      (long long)Nn * E, (long long)Nn * E, (long long)Nn * Nn, lrow, Nn);

  // 4) O' = P' V  (gemm128: 768 blocks)
  gemm128<EPI_BF16><<<dim3(6 * 16, 1, Bb), 256, 0, stream>>>(
      S, Vt, O, nullptr, 6, Nn, 1.f, Nn, Nn, D,
      (long long)Nn * Nn, (long long)D * Nn, (long long)Nn * D);

  // 5) h = LN(xb + O'/l)
  ln1_kernel<<<M, 256, 0, stream>>>(xb, O, lrow, g1, be1, hb);

  // 6) hidden = gelu(h W1 + b1)  (gemm256: 768 blocks)
  gemm256<EPI_GELU_BIAS><<<dim3(12 * 64, 1, 1), 512, 0, stream>>>(
      hb, w1t, hidden, b1, 12, D, 1.f, D, D, F, 0, 0, 0, nullptr, 0);

  // 7) outf = hidden W2 + b2  (gemm128: 768 blocks, bf16 out)
  gemm128<EPI_BF16_BIAS><<<dim3(6 * 128, 1, 1), 256, 0, stream>>>(
      hidden, w2t, outf, b2, 6, F, 1.f, F, F, D, 0, 0, 0);

  // 8) y = LN(h + outf)
  ln2_kernel<<<M, 256, 0, stream>>>(hb, outf, g2, be2, (float*)d_out);
}

// Round 13
// 469.803 us; speedup vs baseline: 1.0370x; 1.0370x over previous
//
#include <hip/hip_runtime.h>
#include <hip/hip_bf16.h>
#include <math.h>

// ---------- types / helpers ----------
using u16 = unsigned short;
typedef __bf16 bf16x8 __attribute__((ext_vector_type(8)));
typedef float f32x4 __attribute__((ext_vector_type(4)));
typedef u16 u16x8 __attribute__((ext_vector_type(8)));

__device__ __forceinline__ u16 f2b(float f) {
  union { float f; unsigned u; } c; c.f = f;
  unsigned r = c.u + 0x7fffu + ((c.u >> 16) & 1u);
  return (u16)(r >> 16);
}
__device__ __forceinline__ float b2f(u16 h) {
  union { unsigned u; float f; } c; c.u = ((unsigned)h) << 16;
  return c.f;
}

// tanh-form GELU (max |err| vs exact ~3e-4 << bf16 rounding)
__device__ __forceinline__ float fast_gelu(float t) {
  float y = fminf(1.5957691216f * t + 0.07135481283f * t * t * t, 80.f);
  float e = __expf(y);
  return t * e * (1.0f / (e + 1.0f));
}

#define EPI_BF16 0
#define EPI_EXP_SUM 1
#define EPI_GELU_BIAS 2
#define EPI_BF16_BIAS 4

#define GLDS16(src, dst)                                                     \
  __builtin_amdgcn_global_load_lds(                                          \
      (const __attribute__((address_space(1))) void*)(src),                  \
      (__attribute__((address_space(3))) void*)(dst), 16, 0, 0)

// bijective XCD swizzle (m204)
__device__ __forceinline__ int xswz(int o, int n) {
  int q = n >> 3, r = n & 7, x = o & 7, i = o >> 3;
  return (x < r ? x * (q + 1) : r * (q + 1) + (x - r) * q) + i;
}

template <int EPI>
__device__ __forceinline__ void epi_store(
    void* Cg, const float* bias, float v, long long off, int ccol, float scale)
{
  if (EPI == EPI_BF16) {
    ((u16*)Cg)[off] = f2b(v);
  } else if (EPI == EPI_GELU_BIAS) {
    ((u16*)Cg)[off] = f2b(fast_gelu(v + bias[ccol]));
  } else {  // EPI_BF16_BIAS
    ((u16*)Cg)[off] = f2b(v + bias[ccol]);
  }
}

// ---------- 128x256 BK=32 dbuf bf16 GEMM — TLP-first structure ----------
// 512 thr = 8 waves (2M x 4N); per-wave 64x64 = acc[4][4] (64 regs).
// LDS 48KB: 2 buf x {A[128x32] 8KB, B[256x32] 16KB} -> 2 blocks/CU
// -> 4 waves/SIMD: co-resident block hides the per-step vmcnt(0) drain
// (m97/m114 mechanism: implicit TLP beats explicit pipelining).
// Per step: stage t+1 (3 GLDS/wave) | read 8 frags | 16 MFMA | drain | barrier.
template <int EPI>
__global__ __launch_bounds__(512, 4) void gemmW(
    const u16* __restrict__ Ag, const u16* __restrict__ Bg,
    void* __restrict__ Cg, const float* __restrict__ bias,
    int nbx, int K, float scale, int lda, int ldb, int ldc,
    long long sAz, long long sBz, long long sCz,
    float* __restrict__ lsum, int lzs)
{
  __shared__ __align__(16) u16 lds[24576];  // 49152 B

  const int tid = threadIdx.x;
  const int wave = tid >> 6, lane = tid & 63;
  const int wr = wave >> 2, wc = wave & 3;         // 2 x 4 wave grid
  const int id = xswz(blockIdx.x, gridDim.x);
  const int bx = id % nbx, by = id / nbx;
  const int m0 = by * 128, n0 = bx * 256;
  const long long z = blockIdx.z;
  const u16* A = Ag + z * sAz + (long long)m0 * lda;
  const u16* B = Bg + z * sBz + (long long)n0 * ldb;

  // A staging: 16 rows/wave (1 GLDS); B: 32 rows/wave (2 GLDS)
  const int rA = wave * 16 + (lane >> 2);
  const int sA = (lane & 3) ^ ((rA >> 1) & 3);     // inverse-swizzled src slot
  const u16* pa = A + (long long)rA * lda + sA * 8;
  const int rB = wave * 32 + (lane >> 2);
  const int sB = (lane & 3) ^ ((rB >> 1) & 3);
  const u16* pb0 = B + (long long)rB * ldb + sB * 8;
  const u16* pb1 = pb0 + (long long)16 * ldb;      // row+16: same swizzle slot
  const int dA = wave * 512;                        // u16, within 4096-u16 A panel
  const int dB0 = wave * 1024, dB1 = wave * 1024 + 512;  // within 8192-u16 B panel

  // frag read byte offsets (swizzled), within A(8KB)/B(16KB) panels
  int offA[4], offB[4];
#pragma unroll
  for (int f = 0; f < 4; ++f) {
    int ra = wr * 64 + f * 16 + (lane & 15);
    int ba = ra * 64 + ((lane >> 4) << 4);
    offA[f] = ba ^ (((ba >> 7) & 3) << 4);
    int rb = wc * 64 + f * 16 + (lane & 15);
    int bb = rb * 64 + ((lane >> 4) << 4);
    offB[f] = bb ^ (((bb >> 7) & 3) << 4);
  }

  f32x4 acc[4][4];
#pragma unroll
  for (int m = 0; m < 4; ++m)
#pragma unroll
    for (int n = 0; n < 4; ++n) acc[m][n] = f32x4{0.f, 0.f, 0.f, 0.f};

  const char* ldsc = (const char*)lds;
  const int NT = K >> 5;  // K-steps of 32 (all K here are multiples of 128)

  // prologue: stage step 0 into buf 0
  GLDS16(pa, lds + dA);
  GLDS16(pb0, lds + 4096 + dB0);
  GLDS16(pb1, lds + 4096 + dB1);
  asm volatile("s_waitcnt vmcnt(0)" ::: "memory");
  asm volatile("s_barrier" ::: "memory");

  for (int t = 0; t < NT; ++t) {
    const int kc = (t + 1 < NT ? t + 1 : 0) << 5;  // wrap keeps counts uniform
    const char* cur = ldsc + (t & 1) * 24576;       // bytes
    u16* nxt = lds + ((t & 1) ^ 1) * 12288;         // u16

    // stage step t+1 (writes buffer last read at step t-1: safe post-barrier)
    GLDS16(pa + kc, nxt + dA);
    GLDS16(pb0 + kc, nxt + 4096 + dB0);
    GLDS16(pb1 + kc, nxt + 4096 + dB1);

    bf16x8 Af[4], Bf[4];
#pragma unroll
    for (int f = 0; f < 4; ++f) {
      Af[f] = *(const bf16x8*)(cur + offA[f]);
      Bf[f] = *(const bf16x8*)(cur + 8192 + offB[f]);
    }
    __builtin_amdgcn_s_setprio(1);
#pragma unroll
    for (int m = 0; m < 4; ++m)
#pragma unroll
      for (int n = 0; n < 4; ++n)
        acc[m][n] = __builtin_amdgcn_mfma_f32_16x16x32_bf16(Af[m], Bf[n], acc[m][n], 0, 0, 0);
    __builtin_amdgcn_s_setprio(0);

    asm volatile("s_waitcnt vmcnt(0)" ::: "memory");  // step t+1 data landed
    asm volatile("s_barrier" ::: "memory");
  }

  // epilogue (m89 C/D layout)
  if (EPI == EPI_EXP_SUM) {
#pragma unroll
    for (int mf = 0; mf < 4; ++mf) {
      const int crow = m0 + wr * 64 + mf * 16 + (lane >> 4) * 4;
      float part[4] = {0.f, 0.f, 0.f, 0.f};
#pragma unroll
      for (int nf = 0; nf < 4; ++nf) {
        const int ccol = n0 + wc * 64 + nf * 16 + (lane & 15);
#pragma unroll
        for (int j = 0; j < 4; ++j) {
          const float p = __expf(fminf(acc[mf][nf][j] * scale, 60.f));
          const u16 ub = f2b(p);
          ((u16*)Cg)[(long long)(crow + j) * ldc + ccol + z * sCz] = ub;
          part[j] += b2f(ub);  // sum the rounded value PV will read
        }
      }
#pragma unroll
      for (int j = 0; j < 4; ++j) {
        float s = part[j];
        s += __shfl_xor(s, 1); s += __shfl_xor(s, 2);
        s += __shfl_xor(s, 4); s += __shfl_xor(s, 8);
        if ((lane & 15) == 0)
          atomicAdd(&lsum[(long long)z * lzs + crow + j], s);
      }
    }
  } else {
#pragma unroll
    for (int mf = 0; mf < 4; ++mf) {
#pragma unroll
      for (int nf = 0; nf < 4; ++nf) {
        const int crow = m0 + wr * 64 + mf * 16 + (lane >> 4) * 4;
        const int ccol = n0 + wc * 64 + nf * 16 + (lane & 15);
#pragma unroll
        for (int j = 0; j < 4; ++j) {
          const long long off = (long long)(crow + j) * ldc + ccol + z * sCz;
          epi_store<EPI>(Cg, bias, acc[mf][nf][j], off, ccol, scale);
        }
      }
    }
  }
}

// ---------- zero f32 buffer ----------
__global__ __launch_bounds__(256) void zero_f32(float* __restrict__ p, int n) {
  const int i = blockIdx.x * 256 + threadIdx.x;
  if (i < n) p[i] = 0.f;
}

// ---------- cast x fp32 -> bf16 ----------
__global__ __launch_bounds__(256) void cast_f32_bf16(
    const float* __restrict__ x, u16* __restrict__ y, long long n4)
{
  const long long i = (long long)blockIdx.x * 256 + threadIdx.x;
  if (i >= n4) return;
  const float4 v = ((const float4*)x)[i];
  ushort4 o;
  o.x = f2b(v.x); o.y = f2b(v.y); o.z = f2b(v.z); o.w = f2b(v.w);
  ((ushort4*)y)[i] = o;
}

// ---------- transpose (+cast) : dst[c*R + r] = src[r*ldsrc + c] ----------
template <bool SRC_BF16>
__global__ __launch_bounds__(256) void transpose_cast(
    const void* __restrict__ srcv, u16* __restrict__ dst, int R, int C, int ldsrc,
    long long szSrc, long long szDst)
{
  __shared__ float tile[32][33];
  const long long zs = (long long)blockIdx.z * szSrc;
  const long long zd = (long long)blockIdx.z * szDst;
  const int c0 = blockIdx.x * 32, r0 = blockIdx.y * 32;
  const int tx = threadIdx.x & 31, ty = threadIdx.x >> 5;
#pragma unroll
  for (int i = 0; i < 4; ++i) {
    const int r = r0 + ty + i * 8;
    float v;
    if (SRC_BF16) v = b2f(((const u16*)srcv)[zs + (long long)r * ldsrc + c0 + tx]);
    else          v = ((const float*)srcv)[zs + (long long)r * ldsrc + c0 + tx];
    tile[ty + i * 8][tx] = v;
  }
  __syncthreads();
#pragma unroll
  for (int i = 0; i < 4; ++i) {
    const int c = c0 + ty + i * 8;
    dst[zd + (long long)c * R + r0 + tx] = f2b(tile[tx][ty + i * 8]);
  }
}

// ---------- add + layernorm (LN1: bf16 x + O'/l) ----------
__global__ __launch_bounds__(256) void ln1_kernel(
    const u16* __restrict__ xb, const u16* __restrict__ O,
    const float* __restrict__ l,
    const float* __restrict__ g, const float* __restrict__ be,
    u16* __restrict__ h)
{
  __shared__ float red[8];
  const long long row = blockIdx.x;
  const u16* xr = xb + row * 768;
  const u16* orow = O + row * 768;
  const float invl = 1.0f / l[row];
  const int t = threadIdx.x, base = t * 3;

  float v[3];
#pragma unroll
  for (int j = 0; j < 3; ++j) v[j] = b2f(xr[base + j]) + b2f(orow[base + j]) * invl;
  float s = v[0] + v[1] + v[2];
  float ss = v[0] * v[0] + v[1] * v[1] + v[2] * v[2];
  for (int o = 32; o; o >>= 1) { s += __shfl_xor(s, o); ss += __shfl_xor(ss, o); }
  if ((t & 63) == 0) { red[t >> 6] = s; red[4 + (t >> 6)] = ss; }
  __syncthreads();
  s = red[0] + red[1] + red[2] + red[3];
  ss = red[4] + red[5] + red[6] + red[7];
  const float mu = s * (1.0f / 768.0f);
  const float var = ss * (1.0f / 768.0f) - mu * mu;
  const float inv = rsqrtf(var + 1e-5f);
#pragma unroll
  for (int j = 0; j < 3; ++j) {
    const float o = (v[j] - mu) * inv * g[base + j] + be[base + j];
    h[row * 768 + base + j] = f2b(o);
  }
}

__global__ __launch_bounds__(256) void ln2_kernel(
    const u16* __restrict__ h, const u16* __restrict__ ob,
    const float* __restrict__ g, const float* __restrict__ be,
    float* __restrict__ y)
{
  __shared__ float red[8];
  const long long row = blockIdx.x;
  const u16* hr = h + row * 768;
  const u16* orow = ob + row * 768;
  const int t = threadIdx.x, base = t * 3;

  float v[3];
#pragma unroll
  for (int j = 0; j < 3; ++j) v[j] = b2f(hr[base + j]) + b2f(orow[base + j]);
  float s = v[0] + v[1] + v[2];
  float ss = v[0] * v[0] + v[1] * v[1] + v[2] * v[2];
  for (int o = 32; o; o >>= 1) { s += __shfl_xor(s, o); ss += __shfl_xor(ss, o); }
  if ((t & 63) == 0) { red[t >> 6] = s; red[4 + (t >> 6)] = ss; }
  __syncthreads();
  s = red[0] + red[1] + red[2] + red[3];
  ss = red[4] + red[5] + red[6] + red[7];
  const float mu = s * (1.0f / 768.0f);
  const float var = ss * (1.0f / 768.0f) - mu * mu;
  const float inv = rsqrtf(var + 1e-5f);
#pragma unroll
  for (int j = 0; j < 3; ++j) {
    y[row * 768 + base + j] = (v[j] - mu) * inv * g[base + j] + be[base + j];
  }
}

// ---------- launch ----------
extern "C" void kernel_launch(void* const* d_in, const int* in_sizes, int n_in,
                              void* d_out, int out_size, void* d_ws, size_t ws_size,
                              hipStream_t stream)
{
  const int Bb = 8, Nn = 2048, D = 768, F = 3072, E = 1536;
  const int M = Bb * Nn;
  const long long MD = (long long)M * D;

  const float* x   = (const float*)d_in[0];
  const float* Wq  = (const float*)d_in[1];
  const float* Wk  = (const float*)d_in[2];
  const float* Wv  = (const float*)d_in[3];
  const float* g1  = (const float*)d_in[4];
  const float* be1 = (const float*)d_in[5];
  const float* W1  = (const float*)d_in[6];
  const float* b1  = (const float*)d_in[7];
  const float* W2  = (const float*)d_in[8];
  const float* b2  = (const float*)d_in[9];
  const float* g2  = (const float*)d_in[10];
  const float* be2 = (const float*)d_in[11];

  // d_out carve: xb + Wq/Wk^T fused + Wv^T (all dead before ln2 writes d_out)
  u16* xb   = (u16*)d_out;                 // [16384][768]
  u16* wqkt = xb + MD;                     // [1536][768]
  u16* wvt  = wqkt + (size_t)E * D;        // [768][768]

  // ws carve
  char* w = (char*)d_ws;
  size_t off = 0;
  auto alloc = [&](size_t bytes) { void* p = w + off; off += bytes; return p; };
  u16* w1t = (u16*)alloc((size_t)F * D * 2);        // [3072][768]
  u16* w2t = (u16*)alloc((size_t)D * F * 2);        // [768][3072]
  u16* hb  = (u16*)alloc((size_t)MD * 2);           // LN1 out
  float* lrow = (float*)alloc((size_t)M * 4);       // softmax row sums
  u16* qk  = (u16*)alloc((size_t)M * E * 2);        // [16384][1536]
  u16* Vt  = (u16*)alloc((size_t)Bb * D * Nn * 2);  // [8][768][2048]
  u16* S   = (u16*)alloc((size_t)Bb * Nn * Nn * 2); // [8][2048][2048] (P')
  u16* O   = (u16*)alloc((size_t)MD * 2);
  // phase-B overlays on dead attention block:
  u16* hidden = qk;                                  // [16384][3072]
  u16* outf   = qk + (size_t)M * F;                  // bf16 FFN2 out

  const dim3 tcb(256);
  const float scl = 0.03608439182435161f;  // 1/sqrt(768)

  // 0) zero row-sum buffer; casts + weight transposes
  zero_f32<<<M / 256, 256, 0, stream>>>(lrow, M);
  cast_f32_bf16<<<(unsigned)(MD / 4 / 256), 256, 0, stream>>>(x, xb, MD / 4);
  transpose_cast<false><<<dim3(D / 32, D / 32, 1), tcb, 0, stream>>>(Wq, wqkt, D, D, D, 0, 0);
  transpose_cast<false><<<dim3(D / 32, D / 32, 1), tcb, 0, stream>>>(Wk, wqkt + D * D, D, D, D, 0, 0);
  transpose_cast<false><<<dim3(D / 32, D / 32, 1), tcb, 0, stream>>>(Wv, wvt, D, D, D, 0, 0);
  transpose_cast<false><<<dim3(F / 32, D / 32, 1), tcb, 0, stream>>>(W1, w1t, D, F, F, 0, 0);
  transpose_cast<false><<<dim3(D / 32, F / 32, 1), tcb, 0, stream>>>(W2, w2t, F, D, D, 0, 0);

  // 1) fused QK projection: 128x256 tiles -> 128*6 = 768 blocks
  gemmW<EPI_BF16><<<dim3(6 * 128, 1, 1), 512, 0, stream>>>(
      xb, wqkt, qk, nullptr, 6, D, 1.f, D, D, E, 0, 0, 0, nullptr, 0);

  // 2) Vt as GEMM: Vt[z][d][n] = wvt[d][:] . x[z][n][:]  (6*8 x 8 = 384 blocks)
  gemmW<EPI_BF16><<<dim3(8 * 6, 1, Bb), 512, 0, stream>>>(
      wvt, xb, Vt, nullptr, 8, D, 1.f, D, D, Nn,
      0, (long long)Nn * D, (long long)D * Nn, nullptr, 0);

  // 3) P' = exp(Q K^T / sqrt(D)) + row sums  (16*8 x 8 = 1024 blocks)
  gemmW<EPI_EXP_SUM><<<dim3(8 * 16, 1, Bb), 512, 0, stream>>>(
      qk, qk + D, S, nullptr, 8, D, scl, E, E, Nn,
      (long long)Nn * E, (long long)Nn * E, (long long)Nn * Nn, lrow, Nn);

  // 4) O' = P' V  (16*3 x 8 = 384 blocks)
  gemmW<EPI_BF16><<<dim3(3 * 16, 1, Bb), 512, 0, stream>>>(
      S, Vt, O, nullptr, 3, Nn, 1.f, Nn, Nn, D,
      (long long)Nn * Nn, (long long)D * Nn, (long long)Nn * D, nullptr, 0);

  // 5) h = LN(xb + O'/l)
  ln1_kernel<<<M, 256, 0, stream>>>(xb, O, lrow, g1, be1, hb);

  // 6) hidden = gelu(h W1 + b1)  (128*12 = 1536 blocks)
  gemmW<EPI_GELU_BIAS><<<dim3(12 * 128, 1, 1), 512, 0, stream>>>(
      hb, w1t, hidden, b1, 12, D, 1.f, D, D, F, 0, 0, 0, nullptr, 0);

  // 7) outf = hidden W2 + b2  (128*3 = 384 blocks, bf16 out)
  gemmW<EPI_BF16_BIAS><<<dim3(3 * 128, 1, 1), 512, 0, stream>>>(
      hidden, w2t, outf, b2, 3, F, 1.f, F, F, D, 0, 0, 0, nullptr, 0);

  // 8) y = LN(h + outf)
  ln2_kernel<<<M, 256, 0, stream>>>(hb, outf, g2, be2, (float*)d_out);
}